// Round 1
// baseline (731.152 us; speedup 1.0000x reference)
//
#include <hip/hip_runtime.h>
#include <math.h>

// RC thermal scan: t_{s+1} = a*t_s + c_s, a = 1 - DT/(R*C) (constant),
// c_s = (DT/C) * (t_out/R - g*u + A_eff*so).
// One block per batch row (S=4096), 256 threads (4 waves), 16 steps/thread.
//
// R3: exploit that the per-chunk multiplier a^16 is UNIFORM across threads.
// The (m,d) affine-pair scan degenerates to a scan over d with multipliers
// m16^(2^k) known by repeated squaring:
//   - intra-wave: 6 rounds of __shfl_up, zero barriers, no LDS
//   - cross-wave: one 4-float LDS exchange, one barrier
// Barrier count 18 -> 3; sm_m/sm_d gone. Register-lean phases +
// __launch_bounds__(256,8) targets <=64 VGPR -> 8 blocks/CU (32 waves/CU)
// so block-serial scan work hides under other blocks' streaming loads.

#define SLEN 4096
#define THREADS 256
#define PER 16  // SLEN / THREADS

__global__ __launch_bounds__(THREADS, 8) void rc_scan_kernel(
    const float* __restrict__ in,
    const float* __restrict__ rawR,
    const float* __restrict__ rawC,
    const float* __restrict__ rawA,
    const float* __restrict__ rawG,
    float* __restrict__ out)
{
    // Padded staging: stride 17 per 16-group. Conflict-free on both the
    // per-thread contiguous reads (lane stride 17, gcd(17,32)=1) and the
    // phase-1/4 grouped accesses. 17408 B + 16 B wave totals.
    __shared__ float sm_c[256 * 17];
    __shared__ float sm_w[4];

    const int row  = blockIdx.x;
    const int tid  = threadIdx.x;
    const int lane = tid & 63;
    const int wid  = tid >> 6;  // 0..3

    // Bounded params (cheap, every thread computes)
    const float sR = 1.0f / (1.0f + expf(-rawR[0]));
    const float sC = 1.0f / (1.0f + expf(-rawC[0]));
    const float sA = 1.0f / (1.0f + expf(-rawA[0]));
    const float sG = 1.0f / (1.0f + expf(-rawG[0]));
    const float R = 0.0001f + (0.2f - 0.0001f) * sR;
    const float C = 100000.0f + (100000000.0f - 100000.0f) * sC;
    const float A = 0.2f * sA;
    const float g = 1.0f + (20000.0f - 1.0f) * sG;

    const float k     = 900.0f / C;      // DT / C
    const float kinvR = k / R;
    const float a     = 1.0f - kinvR;    // constant step multiplier
    const float kg    = k * g;
    const float kA    = k * A;

    const float4* rowp = (const float4*)(in + (size_t)row * (size_t)(SLEN * 4));

    // t0 = t_in[row, 0] — broadcast read (same address all lanes, cached)
    const float t0 = in[(size_t)row * (size_t)(SLEN * 4)];

    // Phase 1: coalesced float4 load (lane i -> base + i*16B), reduce to c_s,
    // stage into padded LDS. PAD_IDX(tid + 256q) = (tid>>4)*17 + (tid&15)
    // + 272q — hoist the base.
    const int sbase = (tid >> 4) * 17 + (tid & 15);
#pragma unroll
    for (int q = 0; q < PER; ++q) {
        float4 v = rowp[tid + THREADS * q];
        sm_c[sbase + 272 * q] = kinvR * v.y - kg * v.z + kA * v.w;
    }
    __syncthreads();  // barrier 1: staging complete

    // Phase 2: fold this thread's 16 contiguous c into d (t_end = a^16*t_in + d).
    // LDS reads at tid*17 + j: conflict-free, own-cells only.
    const int cbase = tid * 17;
    float d = 0.0f;
#pragma unroll
    for (int j = 0; j < PER; ++j) d = fmaf(a, d, sm_c[cbase + j]);

    const float a2 = a * a, a4 = a2 * a2, a8 = a4 * a4;
    const float m16 = a8 * a8;  // a^16 — uniform across threads

    // Intra-wave inclusive scan of d with uniform multiplier:
    // round k: d += m16^(2^k) * d_{lane-2^k}. No barriers, no LDS.
    float M = m16;
#pragma unroll
    for (int off = 1; off < 64; off <<= 1) {
        float od = __shfl_up(d, off, 64);
        if (lane >= off) d = fmaf(M, od, d);
        M *= M;  // all lanes: M -> m16^(2^(k+1))
    }
    // M == m16^64 == a^1024 (wave-chunk multiplier)

    // Cross-wave exchange: lane 63 holds the wave's inclusive total.
    if (lane == 63) sm_w[wid] = d;
    __syncthreads();  // barrier 2: wave totals visible

    // Wave prefix folded with t0: E = a^(1024*wid)*t0 + sum_{v<wid} a^(1024*(wid-1-v))*W_v
    float E = t0;
    for (int v = 0; v < wid; ++v) E = fmaf(M, E, sm_w[v]);  // wave-uniform loop

    // Exclusive intra-wave d
    float dx = __shfl_up(d, 1, 64);
    if (lane == 0) dx = 0.0f;

    // alpha = m16^lane via binary decomposition (6 mults)
    float alpha = 1.0f, b = m16;
#pragma unroll
    for (int kk = 0; kk < 6; ++kk) {
        if (lane & (1 << kk)) alpha *= b;
        b *= b;
    }

    // Starting temperature for this thread's chunk:
    // t = a^(16*tid)*t0 + D_excl(tid) = alpha*E + dx
    float t = fmaf(alpha, E, dx);

    // Phase 3: replay 16 steps in place (re-read c from LDS, overwrite with t).
    // Own cells only; no sync needed before the overwrite.
#pragma unroll
    for (int j = 0; j < PER; ++j) {
        t = fmaf(a, t, sm_c[cbase + j]);
        sm_c[cbase + j] = t;
    }
    __syncthreads();  // barrier 3: outputs staged

    // Phase 4: coalesced float4 stores. p = PAD_IDX(q*1024 + 4*tid), and the
    // 4 floats stay inside one 16-group (16B-aligned) -> vectorizable reads.
    float* orow = out + (size_t)row * SLEN;
#pragma unroll
    for (int q = 0; q < 4; ++q) {
        const int s0 = q * 1024 + 4 * tid;
        const int p  = ((s0 >> 4) * 17) + (s0 & 15);
        float4 v;
        v.x = sm_c[p + 0];
        v.y = sm_c[p + 1];
        v.z = sm_c[p + 2];
        v.w = sm_c[p + 3];
        *(float4*)(orow + s0) = v;
    }
}

extern "C" void kernel_launch(void* const* d_in, const int* in_sizes, int n_in,
                              void* d_out, int out_size, void* d_ws, size_t ws_size,
                              hipStream_t stream) {
    const float* in   = (const float*)d_in[0];
    const float* rawR = (const float*)d_in[1];
    const float* rawC = (const float*)d_in[2];
    const float* rawA = (const float*)d_in[3];
    const float* rawG = (const float*)d_in[4];
    float* out = (float*)d_out;

    const int B = in_sizes[0] / (SLEN * 4);  // 8192
    rc_scan_kernel<<<dim3(B), dim3(THREADS), 0, stream>>>(
        in, rawR, rawC, rawA, rawG, out);
}

// Round 2
// 720.205 us; speedup vs baseline: 1.0152x; 1.0152x over previous
//
#include <hip/hip_runtime.h>
#include <math.h>

// RC thermal scan: t_{s+1} = a*t_s + c_s, a = 1 - DT/(R*C) (constant),
// c_s = (DT/C) * (t_out/R - g*u + A_eff*so).
// One block per batch row (S=4096), 256 threads (4 waves), 16 steps/thread.
//
// R4: R3's shfl scan kept (3 barriers, no sm_m/sm_d), but the
// __launch_bounds__(256,8) min-waves bound is DROPPED. Forcing VGPR<=64
// either spilled or serialized phase-1's 16-deep float4 load batch
// (+9.2 us vs R0). Occupancy is not binding for BW here: even 4 blocks/CU
// gives ~64x the in-flight bytes needed to saturate HBM (9.2 KB/CU needed
// at 900-cy latency; one block's 4 waves can have 64 KB outstanding).
// Let the compiler keep all 16 loads in flight.

#define SLEN 4096
#define THREADS 256
#define PER 16  // SLEN / THREADS

__global__ __launch_bounds__(THREADS) void rc_scan_kernel(
    const float* __restrict__ in,
    const float* __restrict__ rawR,
    const float* __restrict__ rawC,
    const float* __restrict__ rawA,
    const float* __restrict__ rawG,
    float* __restrict__ out)
{
    // Padded staging: stride 17 per 16-group. Conflict-free on the
    // per-thread contiguous accesses (lane stride 17, gcd(17,32)=1) and
    // <=2-3-way (free) on the grouped phase-1/4 accesses. 17408 B + 16 B.
    __shared__ float sm_c[256 * 17];
    __shared__ float sm_w[4];

    const int row  = blockIdx.x;
    const int tid  = threadIdx.x;
    const int lane = tid & 63;
    const int wid  = tid >> 6;  // 0..3

    // Bounded params. Per-thread cost is ~8 trans-pipe ops; full-kernel cost
    // ~0.5 us — not worth a broadcast dance.
    const float sR = 1.0f / (1.0f + expf(-rawR[0]));
    const float sC = 1.0f / (1.0f + expf(-rawC[0]));
    const float sA = 1.0f / (1.0f + expf(-rawA[0]));
    const float sG = 1.0f / (1.0f + expf(-rawG[0]));
    const float R = 0.0001f + (0.2f - 0.0001f) * sR;
    const float C = 100000.0f + (100000000.0f - 100000.0f) * sC;
    const float A = 0.2f * sA;
    const float g = 1.0f + (20000.0f - 1.0f) * sG;

    const float k     = 900.0f / C;      // DT / C
    const float kinvR = k / R;
    const float a     = 1.0f - kinvR;    // constant step multiplier
    const float kg    = k * g;
    const float kA    = k * A;

    const float4* rowp = (const float4*)(in + (size_t)row * (size_t)(SLEN * 4));

    // t0 = t_in[row, 0] — broadcast read (same address all lanes, cached)
    const float t0 = in[(size_t)row * (size_t)(SLEN * 4)];

    // Phase 1: coalesced float4 load (lane i -> base + i*16B), reduce to c_s,
    // stage into padded LDS. PAD_IDX(tid + 256q) = (tid>>4)*17 + (tid&15)
    // + 272q — base hoisted. Full unroll: compiler batches all 16 loads.
    const int sbase = (tid >> 4) * 17 + (tid & 15);
#pragma unroll
    for (int q = 0; q < PER; ++q) {
        float4 v = rowp[tid + THREADS * q];
        sm_c[sbase + 272 * q] = kinvR * v.y - kg * v.z + kA * v.w;
    }
    __syncthreads();  // barrier 1: staging complete

    // Phase 2: fold this thread's 16 contiguous c into d (t_end = a^16*t_in + d).
    // LDS reads at tid*17 + j: conflict-free, own-cells only.
    const int cbase = tid * 17;
    float d = 0.0f;
#pragma unroll
    for (int j = 0; j < PER; ++j) d = fmaf(a, d, sm_c[cbase + j]);

    const float a2 = a * a, a4 = a2 * a2, a8 = a4 * a4;
    const float m16 = a8 * a8;  // a^16 — uniform across threads

    // Intra-wave inclusive scan of d with uniform multiplier:
    // round k: d += m16^(2^k) * d_{lane-2^k}. No barriers, no LDS.
    float M = m16;
#pragma unroll
    for (int off = 1; off < 64; off <<= 1) {
        float od = __shfl_up(d, off, 64);
        if (lane >= off) d = fmaf(M, od, d);
        M *= M;  // all lanes: M -> m16^(2^(k+1))
    }
    // M == m16^64 == a^1024 (wave-chunk multiplier)

    // Cross-wave exchange: lane 63 holds the wave's inclusive total.
    if (lane == 63) sm_w[wid] = d;
    __syncthreads();  // barrier 2: wave totals visible

    // Wave prefix folded with t0:
    // E = a^(1024*wid)*t0 + sum_{v<wid} a^(1024*(wid-1-v))*W_v
    float E = t0;
    for (int v = 0; v < wid; ++v) E = fmaf(M, E, sm_w[v]);  // wave-uniform

    // Exclusive intra-wave d
    float dx = __shfl_up(d, 1, 64);
    if (lane == 0) dx = 0.0f;

    // alpha = m16^lane via binary decomposition (6 mults)
    float alpha = 1.0f, b = m16;
#pragma unroll
    for (int kk = 0; kk < 6; ++kk) {
        if (lane & (1 << kk)) alpha *= b;
        b *= b;
    }

    // Starting temperature for this thread's chunk:
    // t = a^(16*tid)*t0 + D_excl(tid) = alpha*E + dx
    float t = fmaf(alpha, E, dx);

    // Phase 3: replay 16 steps in place (re-read c from LDS, overwrite with t).
    // Own cells only; no sync needed before the overwrite.
#pragma unroll
    for (int j = 0; j < PER; ++j) {
        t = fmaf(a, t, sm_c[cbase + j]);
        sm_c[cbase + j] = t;
    }
    __syncthreads();  // barrier 3: outputs staged

    // Phase 4: coalesced float4 stores. p = PAD_IDX(q*1024 + 4*tid); the
    // 4 floats stay inside one 16-group.
    float* orow = out + (size_t)row * SLEN;
#pragma unroll
    for (int q = 0; q < 4; ++q) {
        const int s0 = q * 1024 + 4 * tid;
        const int p  = ((s0 >> 4) * 17) + (s0 & 15);
        float4 v;
        v.x = sm_c[p + 0];
        v.y = sm_c[p + 1];
        v.z = sm_c[p + 2];
        v.w = sm_c[p + 3];
        *(float4*)(orow + s0) = v;
    }
}

extern "C" void kernel_launch(void* const* d_in, const int* in_sizes, int n_in,
                              void* d_out, int out_size, void* d_ws, size_t ws_size,
                              hipStream_t stream) {
    const float* in   = (const float*)d_in[0];
    const float* rawR = (const float*)d_in[1];
    const float* rawC = (const float*)d_in[2];
    const float* rawA = (const float*)d_in[3];
    const float* rawG = (const float*)d_in[4];
    float* out = (float*)d_out;

    const int B = in_sizes[0] / (SLEN * 4);  // 8192
    rc_scan_kernel<<<dim3(B), dim3(THREADS), 0, stream>>>(
        in, rawR, rawC, rawA, rawG, out);
}